// Round 5
// baseline (1125.190 us; speedup 1.0000x reference)
//
#include <hip/hip_runtime.h>

typedef unsigned int u32;
typedef unsigned short u16;
typedef __attribute__((ext_vector_type(8))) short bf16x8;
typedef __attribute__((ext_vector_type(4))) float f32x4;

// f32 -> bf16 (RNE)
__device__ __forceinline__ u16 f2b(float f){
  u32 x = __float_as_uint(f);
  u32 r = (x + 0x7fffu + ((x >> 16) & 1u)) >> 16;
  return (u16)r;
}

// ---------- preprocessing ----------

__global__ void k_detect(const u32* __restrict__ ei, int n, u32* __restrict__ flag){
  int t = blockIdx.x * blockDim.x + threadIdx.x;
  u32 v = 0;
  if (t < n) v = ei[2 * t + 1];
  unsigned long long b = __ballot(v != 0u);
  if ((threadIdx.x & 63) == 0 && b) atomicOr(flag, 1u);
}

__global__ void k_conv(const int* __restrict__ ei, int* __restrict__ src, int* __restrict__ dst,
                       int E, const u32* __restrict__ flag){
  int e = blockIdx.x * blockDim.x + threadIdx.x;
  if (e >= E) return;
  bool is64 = (*flag == 0u);
  if (is64){ src[e] = ei[2 * e]; dst[e] = ei[2 * (E + e)]; }
  else     { src[e] = ei[e];     dst[e] = ei[E + e]; }
}

__global__ void k_hist(const int* __restrict__ dst, int* __restrict__ deg, int E){
  int e = blockIdx.x * blockDim.x + threadIdx.x;
  if (e < E) atomicAdd(&deg[dst[e]], 1);
}

// single-block shfl-based scan (exclusive), seg[n] = total
__global__ __launch_bounds__(1024) void k_scan(const int* __restrict__ deg, int* __restrict__ seg, int n){
  __shared__ int wsum[16];
  __shared__ int carry_s;
  int t = threadIdx.x, lane = t & 63, w = t >> 6;
  if (t == 0) carry_s = 0;
  __syncthreads();
  for (int base = 0; base < n; base += 1024){
    int i = base + t;
    int v = (i < n) ? deg[i] : 0;
    int x = v;
    #pragma unroll
    for (int off = 1; off < 64; off <<= 1){
      int y = __shfl_up(x, off);
      if (lane >= off) x += y;
    }
    if (lane == 63) wsum[w] = x;
    __syncthreads();
    if (w == 0 && lane < 16){
      int sv = wsum[lane];
      #pragma unroll
      for (int off = 1; off < 16; off <<= 1){
        int y = __shfl_up(sv, off);
        if (lane >= off) sv += y;
      }
      wsum[lane] = sv;
    }
    __syncthreads();
    int woff = (w > 0) ? wsum[w - 1] : 0;
    int carry = carry_s;
    int incl = carry + woff + x;
    if (i < n) seg[i] = incl - v;
    __syncthreads();
    if (t == 1023) carry_s = incl;
    __syncthreads();
  }
  if (threadIdx.x == 0) seg[n] = carry_s;
}

__global__ void k_scatter(const int* __restrict__ src, const int* __restrict__ dst,
                          const int* __restrict__ seg, int* __restrict__ cur,
                          int* __restrict__ ssrc, int* __restrict__ sdst,
                          int* __restrict__ seid, int E){
  int e = blockIdx.x * blockDim.x + threadIdx.x;
  if (e >= E) return;
  int d = dst[e];
  int pos = seg[d] + atomicAdd(&cur[d], 1);
  ssrc[pos] = src[e];
  sdst[pos] = d;
  seid[pos] = e;
}

// materialize edge_attr in dst-sorted order as bf16: ea2[p][0:32] = bf16(eattr[seid[p]])
__global__ void k_sorte(const int* __restrict__ seid, const float* __restrict__ eattr,
                        u16* __restrict__ ea2, int E){
  int e = blockIdx.x * blockDim.x + threadIdx.x;
  if (e >= E) return;
  const float4* srow = (const float4*)(eattr + (size_t)seid[e] * 32);
  u32 pk[16];
  #pragma unroll
  for (int i = 0; i < 8; i++){
    float4 v = srow[i];
    pk[2*i]   = (u32)f2b(v.x) | ((u32)f2b(v.y) << 16);
    pk[2*i+1] = (u32)f2b(v.z) | ((u32)f2b(v.w) << 16);
  }
  uint4* drow = (uint4*)(ea2 + (size_t)e * 32);
  drow[0] = make_uint4(pk[0], pk[1], pk[2], pk[3]);
  drow[1] = make_uint4(pk[4], pk[5], pk[6], pk[7]);
  drow[2] = make_uint4(pk[8], pk[9], pk[10], pk[11]);
  drow[3] = make_uint4(pk[12], pk[13], pk[14], pk[15]);
}

// ---------- node transform: xl = A@Wl, xr = A@Wr (all f32; W [128,128]) ----------
__global__ __launch_bounds__(256) void k_gemm(const float* __restrict__ A,
    const float* __restrict__ Wl, const float* __restrict__ Wr,
    float* __restrict__ xl, float* __restrict__ xr, int nrows)
{
  __shared__ float sA[32][128];
  __shared__ float sW[32][256];
  int t  = threadIdx.x;
  int rb = blockIdx.x * 32;

  #pragma unroll
  for (int i = 0; i < 4; i++){
    int f = t * 16 + i * 4;
    int r = f >> 7, c = f & 127;
    int gr = rb + r;
    float4 v = make_float4(0.f, 0.f, 0.f, 0.f);
    if (gr < nrows) v = *(const float4*)(A + (size_t)gr * 128 + c);
    *(float4*)&sA[r][c] = v;
  }

  int r0 = (t >> 5) * 4;
  int c0 = (t & 31) * 8;
  float acc[4][8];
  #pragma unroll
  for (int r = 0; r < 4; r++)
    #pragma unroll
    for (int j = 0; j < 8; j++) acc[r][j] = 0.f;

  for (int ko = 0; ko < 128; ko += 32){
    __syncthreads();
    #pragma unroll
    for (int i = 0; i < 8; i++){
      int q = i * 256 + t;
      int kl = q >> 6, c = (q & 63) * 4;
      float4 v;
      if (c < 128) v = *(const float4*)(Wl + (size_t)(ko + kl) * 128 + c);
      else         v = *(const float4*)(Wr + (size_t)(ko + kl) * 128 + (c - 128));
      *(float4*)&sW[kl][c] = v;
    }
    __syncthreads();
    #pragma unroll 4
    for (int kl = 0; kl < 32; kl++){
      int k = ko + kl;
      float a0 = sA[r0][k], a1 = sA[r0 + 1][k], a2 = sA[r0 + 2][k], a3 = sA[r0 + 3][k];
      float4 wA = *(float4*)&sW[kl][c0];
      float4 wB = *(float4*)&sW[kl][c0 + 4];
      float wv[8] = { wA.x, wA.y, wA.z, wA.w, wB.x, wB.y, wB.z, wB.w };
      #pragma unroll
      for (int j = 0; j < 8; j++){
        acc[0][j] = fmaf(a0, wv[j], acc[0][j]);
        acc[1][j] = fmaf(a1, wv[j], acc[1][j]);
        acc[2][j] = fmaf(a2, wv[j], acc[2][j]);
        acc[3][j] = fmaf(a3, wv[j], acc[3][j]);
      }
    }
  }

  float* outp = (c0 < 128) ? xl : xr;
  int cc = c0 & 127;
  #pragma unroll
  for (int r = 0; r < 4; r++){
    int gr = rb + r0 + r;
    if (gr < nrows){
      *(float4*)(outp + (size_t)gr * 128 + cc)     = make_float4(acc[r][0], acc[r][1], acc[r][2], acc[r][3]);
      *(float4*)(outp + (size_t)gr * 128 + cc + 4) = make_float4(acc[r][4], acc[r][5], acc[r][6], acc[r][7]);
    }
  }
}

// ---------- edge logits via MFMA: one wave per 64 sorted edges ----------
// ea2 (bf16) @ We (bf16 B-frags in VGPR) on matrix cores; epilogue adds gathered
// xj+xi (f32), leaky-relu, att-dot, 16-lane reduce -> logit2[E].
__global__ __launch_bounds__(256) void k_edge(
    const int* __restrict__ ssrc, const int* __restrict__ sdst,
    const u16* __restrict__ ea2,
    const float* __restrict__ xl, const float* __restrict__ xr,
    const float* __restrict__ We, const float* __restrict__ att,
    float2* __restrict__ logit2, int E)
{
  int lane = threadIdx.x & 63;
  long long base = ((long long)blockIdx.x * 4 + (threadIdx.x >> 6)) * 64;
  if (base >= E) return;
  int col = lane & 15, kg = lane >> 4;

  // B fragments of We + att values for this lane's column
  bf16x8 bw[8];
  float attv[8];
  #pragma unroll
  for (int c = 0; c < 8; c++){
    #pragma unroll
    for (int j = 0; j < 8; j++){
      bw[c][j] = (short)f2b(We[(kg * 8 + j) * 128 + c * 16 + col]);
    }
    attv[c] = att[c * 16 + col];
  }

  #pragma unroll 1
  for (int s = 0; s < 4; s++){
    int erow = (int)base + s * 16;
    bf16x8 a = *(const bf16x8*)(ea2 + (size_t)(erow + col) * 32 + kg * 8);
    int p0 = erow + kg * 4;
    int sn0 = ssrc[p0], sn1 = ssrc[p0 + 1], sn2 = ssrc[p0 + 2], sn3 = ssrc[p0 + 3];
    int dn0 = sdst[p0], dn1 = sdst[p0 + 1], dn2 = sdst[p0 + 2], dn3 = sdst[p0 + 3];
    const float* xj0 = xl + (size_t)sn0 * 128 + col;
    const float* xj1 = xl + (size_t)sn1 * 128 + col;
    const float* xj2 = xl + (size_t)sn2 * 128 + col;
    const float* xj3 = xl + (size_t)sn3 * 128 + col;
    const float* xi0 = xr + (size_t)dn0 * 128 + col;
    const float* xi1 = xr + (size_t)dn1 * 128 + col;
    const float* xi2 = xr + (size_t)dn2 * 128 + col;
    const float* xi3 = xr + (size_t)dn3 * 128 + col;

    float la00 = 0.f, la01 = 0.f, la02 = 0.f, la03 = 0.f;   // head 0
    float la10 = 0.f, la11 = 0.f, la12 = 0.f, la13 = 0.f;   // head 1

    #pragma unroll
    for (int c = 0; c < 8; c++){
      f32x4 d = __builtin_amdgcn_mfma_f32_16x16x32_bf16(a, bw[c], (f32x4){0.f, 0.f, 0.f, 0.f}, 0, 0, 0);
      int off = c * 16;
      float av = attv[c];
      float v0 = d[0] + xj0[off] + xi0[off]; v0 = fmaxf(v0, 0.2f * v0);
      float v1 = d[1] + xj1[off] + xi1[off]; v1 = fmaxf(v1, 0.2f * v1);
      float v2 = d[2] + xj2[off] + xi2[off]; v2 = fmaxf(v2, 0.2f * v2);
      float v3 = d[3] + xj3[off] + xi3[off]; v3 = fmaxf(v3, 0.2f * v3);
      if (c < 4){
        la00 = fmaf(v0, av, la00); la01 = fmaf(v1, av, la01);
        la02 = fmaf(v2, av, la02); la03 = fmaf(v3, av, la03);
      } else {
        la10 = fmaf(v0, av, la10); la11 = fmaf(v1, av, la11);
        la12 = fmaf(v2, av, la12); la13 = fmaf(v3, av, la13);
      }
    }
    // reduce across the 16 lanes (channel columns) of each group
    #pragma unroll
    for (int off = 1; off < 16; off <<= 1){
      la00 += __shfl_xor(la00, off); la01 += __shfl_xor(la01, off);
      la02 += __shfl_xor(la02, off); la03 += __shfl_xor(la03, off);
      la10 += __shfl_xor(la10, off); la11 += __shfl_xor(la11, off);
      la12 += __shfl_xor(la12, off); la13 += __shfl_xor(la13, off);
    }
    if (col == 0){
      if (p0     < E) logit2[p0]     = make_float2(la00, la10);
      if (p0 + 1 < E) logit2[p0 + 1] = make_float2(la01, la11);
      if (p0 + 2 < E) logit2[p0 + 2] = make_float2(la02, la12);
      if (p0 + 3 < E) logit2[p0 + 3] = make_float2(la03, la13);
    }
  }
}

// ---------- slim per-node reduce: exp + weighted sum + epilogue ----------
template<int RELU>
__global__ __launch_bounds__(256) void k_seg2(
    const int* __restrict__ seg, const int* __restrict__ ssrc,
    const float2* __restrict__ logit2,
    const float* __restrict__ xl, const float* __restrict__ bias,
    float* __restrict__ out, int N)
{
  int wid  = blockIdx.x * 4 + (threadIdx.x >> 6);
  int lane = threadIdx.x & 63;
  if (wid >= N) return;
  int c0 = lane * 2, head = lane >> 5;

  int p0 = seg[wid], p1 = seg[wid + 1];
  float2 bv = *(const float2*)(bias + c0);
  if (p0 == p1){
    float r0 = bv.x, r1 = bv.y;
    if (RELU){ r0 = fmaxf(r0, 0.f); r1 = fmaxf(r1, 0.f); }
    *(float2*)(out + (size_t)wid * 128 + c0) = make_float2(r0, r1);
    return;
  }

  float s = 0.f, o0 = 0.f, o1 = 0.f;
  int sn = ssrc[p0];
  float2 lg2 = logit2[p0];
  float2 xj = *(const float2*)(xl + (size_t)sn * 128 + c0);
  for (int p = p0; p < p1; ++p){
    float2 xjc = xj;
    float lc = head ? lg2.y : lg2.x;
    if (p + 1 < p1){
      int s2 = ssrc[p + 1];
      lg2 = logit2[p + 1];
      xj = *(const float2*)(xl + (size_t)s2 * 128 + c0);
    }
    float ex = __expf(fminf(lc, 80.f));
    s += ex;
    o0 = fmaf(ex, xjc.x, o0);
    o1 = fmaf(ex, xjc.y, o1);
  }
  float inv = 1.0f / (s + 1e-16f);
  float r0 = fmaf(o0, inv, bv.x);
  float r1 = fmaf(o1, inv, bv.y);
  if (RELU){ r0 = fmaxf(r0, 0.f); r1 = fmaxf(r1, 0.f); }
  *(float2*)(out + (size_t)wid * 128 + c0) = make_float2(r0, r1);
}

// ---------- launch ----------
extern "C" void kernel_launch(void* const* d_in, const int* in_sizes, int n_in,
                              void* d_out, int out_size, void* d_ws, size_t ws_size,
                              hipStream_t stream)
{
  const float* x     = (const float*)d_in[0];
  const int*   ei    = (const int*)  d_in[1];
  const float* eattr = (const float*)d_in[2];
  const float* Wp[3][5];
  for (int l = 0; l < 3; l++)
    for (int j = 0; j < 5; j++)
      Wp[l][j] = (const float*)d_in[3 + l * 5 + j];

  int N = in_sizes[0] / 128;
  int E = in_sizes[2] / 32;

  char* w = (char*)d_ws;
  auto alloc = [&](size_t bytes) -> char* {
    char* p = w; w += (bytes + 255) & ~(size_t)255; return p;
  };
  float* xl   = (float*)alloc((size_t)N * 128 * 4);
  float* xr   = (float*)alloc((size_t)N * 128 * 4);   // also inter-layer h buffer
  u16*   ea2  = (u16*)  alloc((size_t)(E + 64) * 32 * 2);
  float2* lgt = (float2*)alloc((size_t)E * 8);
  int* srcA   = (int*)alloc((size_t)E * 4);
  int* dstA   = (int*)alloc((size_t)E * 4);
  int* ssrc   = (int*)alloc((size_t)(E + 64) * 4);
  int* sdst   = (int*)alloc((size_t)(E + 64) * 4);
  int* seid   = (int*)alloc((size_t)E * 4);
  int* deg    = (int*)alloc((size_t)N * 4);
  int* cur    = (int*)alloc((size_t)N * 4);
  int* seg    = (int*)alloc((size_t)(N + 1) * 4);
  u32* flag   = (u32*)alloc(256);

  hipMemsetAsync(deg,  0, (size_t)N * 4, stream);
  hipMemsetAsync(cur,  0, (size_t)N * 4, stream);
  hipMemsetAsync(flag, 0, 4, stream);
  hipMemsetAsync(ssrc + E, 0, 64 * 4, stream);   // pad: valid node index 0
  hipMemsetAsync(sdst + E, 0, 64 * 4, stream);

  int ndet = (E < 16384) ? E : 16384;
  k_detect<<<(ndet + 255) / 256, 256, 0, stream>>>((const u32*)ei, ndet, flag);
  int gE = (E + 255) / 256;
  k_conv<<<gE, 256, 0, stream>>>(ei, srcA, dstA, E, flag);
  k_hist<<<gE, 256, 0, stream>>>(dstA, deg, E);
  k_scan<<<1, 1024, 0, stream>>>(deg, seg, N);
  k_scatter<<<gE, 256, 0, stream>>>(srcA, dstA, seg, cur, ssrc, sdst, seid, E);
  k_sorte<<<gE, 256, 0, stream>>>(seid, eattr, ea2, E);

  int gG = (N + 31) / 32;
  int gS = (N + 3) / 4;

  const float* hin = x;
  for (int l = 0; l < 3; l++){
    k_gemm<<<gG, 256, 0, stream>>>(hin, Wp[l][0], Wp[l][1], xl, xr, N);
    k_edge<<<gE, 256, 0, stream>>>(ssrc, sdst, ea2, xl, xr, Wp[l][2], Wp[l][3], lgt, E);
    float* outp = (l == 2) ? (float*)d_out : xr;
    if (l == 2) k_seg2<0><<<gS, 256, 0, stream>>>(seg, ssrc, lgt, xl, Wp[l][4], outp, N);
    else        k_seg2<1><<<gS, 256, 0, stream>>>(seg, ssrc, lgt, xl, Wp[l][4], outp, N);
    hin = xr;
  }
}

// Round 6
// 781.663 us; speedup vs baseline: 1.4395x; 1.4395x over previous
//
#include <hip/hip_runtime.h>

typedef unsigned int u32;
typedef unsigned short u16;
typedef __attribute__((ext_vector_type(8))) short bf16x8;
typedef __attribute__((ext_vector_type(4))) float f32x4;

__device__ __forceinline__ u16 f2b(float f){
  u32 x = __float_as_uint(f);
  u32 r = (x + 0x7fffu + ((x >> 16) & 1u)) >> 16;
  return (u16)r;
}
__device__ __forceinline__ float bl(u32 u){ return __uint_as_float(u << 16); }
__device__ __forceinline__ float bh(u32 u){ return __uint_as_float(u & 0xffff0000u); }

// ---------- preprocessing ----------

__global__ void k_detect(const u32* __restrict__ ei, int n, u32* __restrict__ flag){
  int t = blockIdx.x * blockDim.x + threadIdx.x;
  u32 v = 0;
  if (t < n) v = ei[2 * t + 1];
  unsigned long long b = __ballot(v != 0u);
  if ((threadIdx.x & 63) == 0 && b) atomicOr(flag, 1u);
}

__global__ void k_conv(const int* __restrict__ ei, int* __restrict__ src, int* __restrict__ dst,
                       int E, const u32* __restrict__ flag){
  int e = blockIdx.x * blockDim.x + threadIdx.x;
  if (e >= E) return;
  bool is64 = (*flag == 0u);
  if (is64){ src[e] = ei[2 * e]; dst[e] = ei[2 * (E + e)]; }
  else     { src[e] = ei[e];     dst[e] = ei[E + e]; }
}

__global__ void k_hist(const int* __restrict__ dst, int* __restrict__ deg, int E){
  int e = blockIdx.x * blockDim.x + threadIdx.x;
  if (e < E) atomicAdd(&deg[dst[e]], 1);
}

__global__ __launch_bounds__(1024) void k_scan(const int* __restrict__ deg, int* __restrict__ seg, int n){
  __shared__ int wsum[16];
  __shared__ int carry_s;
  int t = threadIdx.x, lane = t & 63, w = t >> 6;
  if (t == 0) carry_s = 0;
  __syncthreads();
  for (int base = 0; base < n; base += 1024){
    int i = base + t;
    int v = (i < n) ? deg[i] : 0;
    int x = v;
    #pragma unroll
    for (int off = 1; off < 64; off <<= 1){
      int y = __shfl_up(x, off);
      if (lane >= off) x += y;
    }
    if (lane == 63) wsum[w] = x;
    __syncthreads();
    if (w == 0 && lane < 16){
      int sv = wsum[lane];
      #pragma unroll
      for (int off = 1; off < 16; off <<= 1){
        int y = __shfl_up(sv, off);
        if (lane >= off) sv += y;
      }
      wsum[lane] = sv;
    }
    __syncthreads();
    int woff = (w > 0) ? wsum[w - 1] : 0;
    int carry = carry_s;
    int incl = carry + woff + x;
    if (i < n) seg[i] = incl - v;
    __syncthreads();
    if (t == 1023) carry_s = incl;
    __syncthreads();
  }
  if (threadIdx.x == 0) seg[n] = carry_s;
}

__global__ void k_scatter(const int* __restrict__ src, const int* __restrict__ dst,
                          const int* __restrict__ seg, int* __restrict__ cur,
                          int* __restrict__ ssrc, int* __restrict__ sdst,
                          int* __restrict__ seid, int E){
  int e = blockIdx.x * blockDim.x + threadIdx.x;
  if (e >= E) return;
  int d = dst[e];
  int pos = seg[d] + atomicAdd(&cur[d], 1);
  ssrc[pos] = src[e];
  sdst[pos] = d;
  seid[pos] = e;
}

// edge_attr in dst-sorted order as bf16
__global__ void k_sorte(const int* __restrict__ seid, const float* __restrict__ eattr,
                        u16* __restrict__ ea2, int E){
  int e = blockIdx.x * blockDim.x + threadIdx.x;
  if (e >= E) return;
  const float4* srow = (const float4*)(eattr + (size_t)seid[e] * 32);
  u32 pk[16];
  #pragma unroll
  for (int i = 0; i < 8; i++){
    float4 v = srow[i];
    pk[2*i]   = (u32)f2b(v.x) | ((u32)f2b(v.y) << 16);
    pk[2*i+1] = (u32)f2b(v.z) | ((u32)f2b(v.w) << 16);
  }
  uint4* drow = (uint4*)(ea2 + (size_t)e * 32);
  drow[0] = make_uint4(pk[0], pk[1], pk[2], pk[3]);
  drow[1] = make_uint4(pk[4], pk[5], pk[6], pk[7]);
  drow[2] = make_uint4(pk[8], pk[9], pk[10], pk[11]);
  drow[3] = make_uint4(pk[12], pk[13], pk[14], pk[15]);
}

// ---------- node transform: xl = A@Wl, xr = A@Wr (f32) + bf16 copies ----------
__global__ __launch_bounds__(256) void k_gemm(const float* __restrict__ A,
    const float* __restrict__ Wl, const float* __restrict__ Wr,
    float* __restrict__ xl, float* __restrict__ xr,
    u16* __restrict__ xlb, u16* __restrict__ xrb, int nrows)
{
  __shared__ float sA[32][128];
  __shared__ float sW[32][256];
  int t  = threadIdx.x;
  int rb = blockIdx.x * 32;

  #pragma unroll
  for (int i = 0; i < 4; i++){
    int f = t * 16 + i * 4;
    int r = f >> 7, c = f & 127;
    int gr = rb + r;
    float4 v = make_float4(0.f, 0.f, 0.f, 0.f);
    if (gr < nrows) v = *(const float4*)(A + (size_t)gr * 128 + c);
    *(float4*)&sA[r][c] = v;
  }

  int r0 = (t >> 5) * 4;
  int c0 = (t & 31) * 8;
  float acc[4][8];
  #pragma unroll
  for (int r = 0; r < 4; r++)
    #pragma unroll
    for (int j = 0; j < 8; j++) acc[r][j] = 0.f;

  for (int ko = 0; ko < 128; ko += 32){
    __syncthreads();
    #pragma unroll
    for (int i = 0; i < 8; i++){
      int q = i * 256 + t;
      int kl = q >> 6, c = (q & 63) * 4;
      float4 v;
      if (c < 128) v = *(const float4*)(Wl + (size_t)(ko + kl) * 128 + c);
      else         v = *(const float4*)(Wr + (size_t)(ko + kl) * 128 + (c - 128));
      *(float4*)&sW[kl][c] = v;
    }
    __syncthreads();
    #pragma unroll 4
    for (int kl = 0; kl < 32; kl++){
      int k = ko + kl;
      float a0 = sA[r0][k], a1 = sA[r0 + 1][k], a2 = sA[r0 + 2][k], a3 = sA[r0 + 3][k];
      float4 wA = *(float4*)&sW[kl][c0];
      float4 wB = *(float4*)&sW[kl][c0 + 4];
      float wv[8] = { wA.x, wA.y, wA.z, wA.w, wB.x, wB.y, wB.z, wB.w };
      #pragma unroll
      for (int j = 0; j < 8; j++){
        acc[0][j] = fmaf(a0, wv[j], acc[0][j]);
        acc[1][j] = fmaf(a1, wv[j], acc[1][j]);
        acc[2][j] = fmaf(a2, wv[j], acc[2][j]);
        acc[3][j] = fmaf(a3, wv[j], acc[3][j]);
      }
    }
  }

  float* outp = (c0 < 128) ? xl : xr;
  u16*   outb = (c0 < 128) ? xlb : xrb;
  int cc = c0 & 127;
  #pragma unroll
  for (int r = 0; r < 4; r++){
    int gr = rb + r0 + r;
    if (gr < nrows){
      *(float4*)(outp + (size_t)gr * 128 + cc)     = make_float4(acc[r][0], acc[r][1], acc[r][2], acc[r][3]);
      *(float4*)(outp + (size_t)gr * 128 + cc + 4) = make_float4(acc[r][4], acc[r][5], acc[r][6], acc[r][7]);
      uint4 pk;
      pk.x = (u32)f2b(acc[r][0]) | ((u32)f2b(acc[r][1]) << 16);
      pk.y = (u32)f2b(acc[r][2]) | ((u32)f2b(acc[r][3]) << 16);
      pk.z = (u32)f2b(acc[r][4]) | ((u32)f2b(acc[r][5]) << 16);
      pk.w = (u32)f2b(acc[r][6]) | ((u32)f2b(acc[r][7]) << 16);
      *(uint4*)(outb + (size_t)gr * 128 + cc) = pk;
    }
  }
}

// ---------- edge kernel: MFMA ea@We + LDS bounce + thread-per-edge epilogue ----------
// wave handles 16-edge tiles (grid-stride). Writes pr2[p] = exp(logit) per head.
__global__ __launch_bounds__(256) void k_edge(
    const int* __restrict__ ssrc, const int* __restrict__ sdst,
    const u16* __restrict__ ea2,
    const u16* __restrict__ xlb, const u16* __restrict__ xrb,
    const float* __restrict__ We, const float* __restrict__ att,
    float2* __restrict__ pr2, int ntiles, int E)
{
  __shared__ float sD[4][16][136];
  int wv = threadIdx.x >> 6, lane = threadIdx.x & 63;
  int col = lane & 15, kg = lane >> 4;
  int er = lane >> 2, q = lane & 3;

  // B fragments of We (once per kernel)
  bf16x8 bw[8];
  #pragma unroll
  for (int c = 0; c < 8; c++)
    #pragma unroll
    for (int j = 0; j < 8; j++)
      bw[c][j] = (short)f2b(We[(kg * 8 + j) * 128 + c * 16 + col]);
  // att slice for this lane's 32 channels
  float attq[32];
  #pragma unroll
  for (int i = 0; i < 8; i++){
    float4 a4 = *(const float4*)(att + q * 32 + i * 4);
    attq[4*i] = a4.x; attq[4*i+1] = a4.y; attq[4*i+2] = a4.z; attq[4*i+3] = a4.w;
  }

  int wid0 = blockIdx.x * 4 + wv;
  int nw = gridDim.x * 4;
  for (int t = wid0; t < ntiles; t += nw){
    int e0 = t * 16;
    bf16x8 a = *(const bf16x8*)(ea2 + (size_t)(e0 + col) * 32 + kg * 8);
    #pragma unroll
    for (int c = 0; c < 8; c++){
      f32x4 d = __builtin_amdgcn_mfma_f32_16x16x32_bf16(a, bw[c], (f32x4){0.f,0.f,0.f,0.f}, 0, 0, 0);
      #pragma unroll
      for (int r = 0; r < 4; r++)
        sD[wv][kg * 4 + r][c * 16 + col] = d[r];
    }
    // same-wave produce->consume; compiler orders LDS ops with lgkmcnt
    int p = e0 + er;
    int sn = ssrc[p], dn = sdst[p];
    const u16* xj = xlb + (size_t)sn * 128 + q * 32;
    const u16* xi = xrb + (size_t)dn * 128 + q * 32;
    uint4 ju0 = *(const uint4*)(xj);
    uint4 ju1 = *(const uint4*)(xj + 8);
    uint4 ju2 = *(const uint4*)(xj + 16);
    uint4 ju3 = *(const uint4*)(xj + 24);
    uint4 iu0 = *(const uint4*)(xi);
    uint4 iu1 = *(const uint4*)(xi + 8);
    uint4 iu2 = *(const uint4*)(xi + 16);
    uint4 iu3 = *(const uint4*)(xi + 24);
    const float* drow = &sD[wv][er][q * 32];

    float acc = 0.f;
    uint4 jq[4] = { ju0, ju1, ju2, ju3 };
    uint4 iq[4] = { iu0, iu1, iu2, iu3 };
    #pragma unroll
    for (int k = 0; k < 4; k++){
      float4 d0 = *(const float4*)(drow + k * 8);
      float4 d1 = *(const float4*)(drow + k * 8 + 4);
      u32 jw[4] = { jq[k].x, jq[k].y, jq[k].z, jq[k].w };
      u32 iw[4] = { iq[k].x, iq[k].y, iq[k].z, iq[k].w };
      float dv[8] = { d0.x, d0.y, d0.z, d0.w, d1.x, d1.y, d1.z, d1.w };
      #pragma unroll
      for (int m = 0; m < 4; m++){
        float v0 = dv[2*m]   + bl(jw[m]) + bl(iw[m]);
        float v1 = dv[2*m+1] + bh(jw[m]) + bh(iw[m]);
        v0 = fmaxf(v0, 0.2f * v0);
        v1 = fmaxf(v1, 0.2f * v1);
        acc = fmaf(v0, attq[k*8 + 2*m], acc);
        acc = fmaf(v1, attq[k*8 + 2*m + 1], acc);
      }
    }
    acc += __shfl_xor(acc, 1);          // q0: head0 sum, q2: head1 sum
    float other = __shfl_xor(acc, 2);
    if (q == 0 && p < E){
      float l0 = fminf(acc, 80.f), l1 = fminf(other, 80.f);
      pr2[p] = make_float2(__expf(l0), __expf(l1));
    }
  }
}

// ---------- slim per-node reduce: sum + weighted sum + epilogue ----------
template<int RELU>
__global__ __launch_bounds__(256) void k_seg2(
    const int* __restrict__ seg, const int* __restrict__ ssrc,
    const float2* __restrict__ pr2,
    const float* __restrict__ xl, const float* __restrict__ bias,
    float* __restrict__ out, int N)
{
  int wid  = blockIdx.x * 4 + (threadIdx.x >> 6);
  int lane = threadIdx.x & 63;
  if (wid >= N) return;
  int c0 = lane * 2, head = lane >> 5;

  int p0 = seg[wid], p1 = seg[wid + 1];
  float2 bv = *(const float2*)(bias + c0);
  if (p0 == p1){
    float r0 = bv.x, r1 = bv.y;
    if (RELU){ r0 = fmaxf(r0, 0.f); r1 = fmaxf(r1, 0.f); }
    *(float2*)(out + (size_t)wid * 128 + c0) = make_float2(r0, r1);
    return;
  }

  float s = 0.f, o0 = 0.f, o1 = 0.f;
  int sn = ssrc[p0];
  float2 pr = pr2[p0];
  float2 xj = *(const float2*)(xl + (size_t)sn * 128 + c0);
  for (int p = p0; p < p1; ++p){
    float2 xjc = xj;
    float ex = head ? pr.y : pr.x;
    if (p + 1 < p1){
      int s2 = ssrc[p + 1];
      pr = pr2[p + 1];
      xj = *(const float2*)(xl + (size_t)s2 * 128 + c0);
    }
    s += ex;
    o0 = fmaf(ex, xjc.x, o0);
    o1 = fmaf(ex, xjc.y, o1);
  }
  float inv = 1.0f / (s + 1e-16f);
  float r0 = fmaf(o0, inv, bv.x);
  float r1 = fmaf(o1, inv, bv.y);
  if (RELU){ r0 = fmaxf(r0, 0.f); r1 = fmaxf(r1, 0.f); }
  *(float2*)(out + (size_t)wid * 128 + c0) = make_float2(r0, r1);
}

// ---------- launch ----------
extern "C" void kernel_launch(void* const* d_in, const int* in_sizes, int n_in,
                              void* d_out, int out_size, void* d_ws, size_t ws_size,
                              hipStream_t stream)
{
  const float* x     = (const float*)d_in[0];
  const int*   ei    = (const int*)  d_in[1];
  const float* eattr = (const float*)d_in[2];
  const float* Wp[3][5];
  for (int l = 0; l < 3; l++)
    for (int j = 0; j < 5; j++)
      Wp[l][j] = (const float*)d_in[3 + l * 5 + j];

  int N = in_sizes[0] / 128;
  int E = in_sizes[2] / 32;

  char* w = (char*)d_ws;
  auto alloc = [&](size_t bytes) -> char* {
    char* p = w; w += (bytes + 255) & ~(size_t)255; return p;
  };
  float* xl   = (float*)alloc((size_t)N * 128 * 4);
  float* xr   = (float*)alloc((size_t)N * 128 * 4);   // also inter-layer h buffer
  u16*   xlb  = (u16*)  alloc((size_t)N * 128 * 2);
  u16*   xrb  = (u16*)  alloc((size_t)N * 128 * 2);
  u16*   ea2  = (u16*)  alloc((size_t)(E + 64) * 32 * 2);
  float2* prb = (float2*)alloc((size_t)E * 8);
  int* srcA   = (int*)alloc((size_t)E * 4);
  int* dstA   = (int*)alloc((size_t)E * 4);
  int* ssrc   = (int*)alloc((size_t)(E + 64) * 4);
  int* sdst   = (int*)alloc((size_t)(E + 64) * 4);
  int* seid   = (int*)alloc((size_t)E * 4);
  int* deg    = (int*)alloc((size_t)N * 4);
  int* cur    = (int*)alloc((size_t)N * 4);
  int* seg    = (int*)alloc((size_t)(N + 1) * 4);
  u32* flag   = (u32*)alloc(256);

  hipMemsetAsync(deg,  0, (size_t)N * 4, stream);
  hipMemsetAsync(cur,  0, (size_t)N * 4, stream);
  hipMemsetAsync(flag, 0, 4, stream);
  hipMemsetAsync(ssrc + E, 0, 64 * 4, stream);   // pad: valid node index 0
  hipMemsetAsync(sdst + E, 0, 64 * 4, stream);

  int ndet = (E < 16384) ? E : 16384;
  k_detect<<<(ndet + 255) / 256, 256, 0, stream>>>((const u32*)ei, ndet, flag);
  int gE = (E + 255) / 256;
  k_conv<<<gE, 256, 0, stream>>>(ei, srcA, dstA, E, flag);
  k_hist<<<gE, 256, 0, stream>>>(dstA, deg, E);
  k_scan<<<1, 1024, 0, stream>>>(deg, seg, N);
  k_scatter<<<gE, 256, 0, stream>>>(srcA, dstA, seg, cur, ssrc, sdst, seid, E);
  k_sorte<<<gE, 256, 0, stream>>>(seid, eattr, ea2, E);

  int gG = (N + 31) / 32;
  int gS = (N + 3) / 4;
  int ntiles = (E + 15) / 16;
  int gEdge = (ntiles + 3) / 4; if (gEdge > 2048) gEdge = 2048;

  const float* hin = x;
  for (int l = 0; l < 3; l++){
    k_gemm<<<gG, 256, 0, stream>>>(hin, Wp[l][0], Wp[l][1], xl, xr, xlb, xrb, N);
    k_edge<<<gEdge, 256, 0, stream>>>(ssrc, sdst, ea2, xlb, xrb, Wp[l][2], Wp[l][3], prb, ntiles, E);
    float* outp = (l == 2) ? (float*)d_out : xr;
    if (l == 2) k_seg2<0><<<gS, 256, 0, stream>>>(seg, ssrc, prb, xl, Wp[l][4], outp, N);
    else        k_seg2<1><<<gS, 256, 0, stream>>>(seg, ssrc, prb, xl, Wp[l][4], outp, N);
    hin = xr;
  }
}